// Round 2
// baseline (26328.033 us; speedup 1.0000x reference)
//
#include <hip/hip_runtime.h>
#include <hip/hip_bf16.h>

// GraphBertEncoder: T=32768 tokens, S=6, D=256, H=8 heads (hd=32), L=4 layers.
// Inputs/outputs are float32 (per reference dtypes). Fully fused: one kernel,
// each block owns TB=4 tokens (24 rows of 256), h stays in LDS across all 4
// layers, writes only h[:,0]. q/k/v stored bf16 in LDS (LDS budget); all
// accumulation fp32.

#define TB 4
#define NROW 24   // TB * S

__device__ __forceinline__ float bf2f(__hip_bfloat16 v) { return __bfloat162float(v); }
__device__ __forceinline__ __hip_bfloat16 f2bf(float v) { return __float2bfloat16(v); }

// LayerNorm over 256 columns for 24 rows; each thread holds column `tid` of all
// rows in z[24]. Normalized values written back into z. redbuf: 64 floats LDS.
__device__ __forceinline__ void ln24_norm(float* z, float* redbuf, float g, float b, int tid) {
  const int lane = tid & 63, wid = tid >> 6;
  #pragma unroll
  for (int cb = 0; cb < 3; ++cb) {
    float s1[8], s2[8];
    #pragma unroll
    for (int q = 0; q < 8; ++q) { float v = z[cb*8+q]; s1[q] = v; s2[q] = v*v; }
    #pragma unroll
    for (int off = 32; off; off >>= 1) {
      #pragma unroll
      for (int q = 0; q < 8; ++q) {
        s1[q] += __shfl_down(s1[q], off, 64);
        s2[q] += __shfl_down(s2[q], off, 64);
      }
    }
    if (lane == 0) {
      #pragma unroll
      for (int q = 0; q < 8; ++q) { redbuf[wid*16+q] = s1[q]; redbuf[wid*16+8+q] = s2[q]; }
    }
    __syncthreads();
    #pragma unroll
    for (int q = 0; q < 8; ++q) {
      float S1 = redbuf[q] + redbuf[16+q] + redbuf[32+q] + redbuf[48+q];
      float S2 = redbuf[8+q] + redbuf[24+q] + redbuf[40+q] + redbuf[56+q];
      float m  = S1 * (1.0f/256.0f);
      float var = S2 * (1.0f/256.0f) - m*m;
      float iv = rsqrtf(var + 1e-5f);
      z[cb*8+q] = (z[cb*8+q] - m) * iv * g + b;
    }
    __syncthreads();
  }
}

__global__ __launch_bounds__(256, 2) void gb_fused_kernel(
    const float* __restrict__ x,
    const float* __restrict__ W_raw, const float* __restrict__ b_raw,
    const float* __restrict__ wl_emb, const float* __restrict__ pos_emb,
    const float* __restrict__ hop_emb,
    const float* __restrict__ ln_g, const float* __restrict__ ln_b,
    const float* __restrict__ Wqkv, const float* __restrict__ bqkv,
    const float* __restrict__ Wo,   const float* __restrict__ bo,
    const float* __restrict__ n1g,  const float* __restrict__ n1b,
    const float* __restrict__ W1,   const float* __restrict__ b1,
    const float* __restrict__ W2,   const float* __restrict__ b2,
    const float* __restrict__ n2g,  const float* __restrict__ n2b,
    const float* __restrict__ W_res, const float* __restrict__ b_res,
    float* __restrict__ out)
{
  __shared__ float hs[NROW][256];                    // 24 KB: h rows (fp32)
  __shared__ __align__(16) char bufraw[NROW*768*2];  // 36 KB: qkv(bf16) / o,gelu(fp32) / x-stage
  __shared__ float attw[8][NROW][8];                 // 6 KB: per-head scores/weights
  __shared__ float redbuf[64];

  __hip_bfloat16 (*qkvs)[768] = (__hip_bfloat16 (*)[768])bufraw;
  float (*fbuf)[256] = (float (*)[256])bufraw;
  float (*xbuf)[128] = (float (*)[128])bufraw;

  const int tid = threadIdx.x;
  const int bt  = blockIdx.x;            // token block: tokens bt*4 .. bt*4+3

  // ---------------- Embedding: stage sub_x rows (idx mapping) ----------------
  for (int idx = tid; idx < TB*6*128; idx += 256) {
    int tt = idx / 768, rem = idx % 768;
    int s = rem >> 7, f = rem & 127;
    int t = bt*TB + tt, g = t >> 7, i = t & 127;
    int node;
    if (s < 2) node = i;
    else { int j = s - 2; node = (j < i) ? j : (j + 1); }
    xbuf[tt*6+s][f] = x[(g*128 + node)*128 + f];
  }
  __syncthreads();

  float z[NROW];
  {
    #pragma unroll
    for (int r = 0; r < NROW; ++r) z[r] = 0.f;
    #pragma unroll 4
    for (int f = 0; f < 128; ++f) {
      float w = W_raw[f*256 + tid];
      #pragma unroll
      for (int r = 0; r < NROW; ++r) z[r] += xbuf[r][f] * w;
    }
    float br  = b_raw[tid];
    float wl  = wl_emb[tid];            // wl_emb[0]
    float hp0 = hop_emb[5*256 + tid];   // dist==1 -> hop id 5
    float hp1 = hop_emb[511*256 + tid]; // dist==0 -> hop id 511
    float p[6];
    #pragma unroll
    for (int s = 0; s < 6; ++s) p[s] = pos_emb[s*256 + tid];
    #pragma unroll
    for (int r = 0; r < NROW; ++r) {
      int s = r % 6;
      z[r] += br + p[s] + wl + ((s < 2) ? hp0 : hp1);
    }
  }
  ln24_norm(z, redbuf, ln_g[tid], ln_b[tid], tid);
  #pragma unroll
  for (int r = 0; r < NROW; ++r) hs[r][tid] = z[r];

  // ---------------- res (nonzero only for first G=256 tokens: bt<64) --------
  float resv[NROW];
  #pragma unroll
  for (int r = 0; r < NROW; ++r) resv[r] = 0.f;
  if (bt < 64) {
    // restage x rows t*128+s (uniform branch: bt is per-block)
    for (int idx = tid; idx < TB*6*128; idx += 256) {
      int tt = idx / 768, rem = idx % 768;
      int s = rem >> 7, f = rem & 127;
      int t = bt*TB + tt;
      xbuf[tt*6+s][f] = x[(t*128 + s)*128 + f];
    }
    __syncthreads();
    #pragma unroll 4
    for (int f = 0; f < 128; ++f) {
      float w = W_res[f*256 + tid];
      #pragma unroll
      for (int r = 0; r < NROW; ++r) resv[r] += xbuf[r][f] * w;
    }
    float brr = b_res[tid];
    #pragma unroll
    for (int r = 0; r < NROW; ++r) resv[r] += brr;
  }

  // ---------------- Transformer layers (all 4, h stays in LDS) -------------
  for (int l = 0; l < 4; ++l) {
    const float* Wqkv_l = Wqkv + l*196608;
    const float* bqkv_l = bqkv + l*768;
    const float* Wo_l   = Wo   + l*65536;
    const float* bo_l   = bo   + l*256;
    const float* W1_l   = W1   + l*262144;
    const float* b1_l   = b1   + l*1024;
    const float* W2_l   = W2   + l*262144;
    const float* b2_l   = b2   + l*256;

    __syncthreads();  // hs ready; previous users of bufraw done

    // ---- QKV: columns stationary per thread, 24 rows in registers ----
    for (int cg = 0; cg < 3; ++cg) {
      int col = cg*256 + tid;
      float acc[NROW];
      #pragma unroll
      for (int r = 0; r < NROW; ++r) acc[r] = 0.f;
      #pragma unroll 4
      for (int kk = 0; kk < 256; ++kk) {
        float w = Wqkv_l[kk*768 + col];
        #pragma unroll
        for (int r = 0; r < NROW; ++r) acc[r] += hs[r][kk] * w;
      }
      float bb = bqkv_l[col];
      #pragma unroll
      for (int r = 0; r < NROW; ++r) qkvs[r][col] = f2bf(acc[r] + bb);
    }
    __syncthreads();

    // ---- attention scores: 8 heads x 24 rows x 6 keys = 1152 dots of 32 ----
    #pragma unroll 1
    for (int it = 0; it < 5; ++it) {
      int idx = it*256 + tid;
      if (idx < 1152) {
        int hh = idx / 144, rem = idx % 144;
        int r = rem / 6, sp = rem % 6;
        int tt6 = (r / 6) * 6;
        float sc = 0.f;
        #pragma unroll
        for (int c = 0; c < 32; ++c)
          sc += bf2f(qkvs[r][hh*32 + c]) * bf2f(qkvs[tt6 + sp][256 + hh*32 + c]);
        attw[hh][r][sp] = sc * 0.17677669529663687f;  // 1/sqrt(32)
      }
    }
    __syncthreads();

    // ---- softmax over 6 (192 independent rows) ----
    if (tid < 192) {
      int hh = tid / 24, r = tid % 24;
      float mx = attw[hh][r][0];
      #pragma unroll
      for (int sp = 1; sp < 6; ++sp) mx = fmaxf(mx, attw[hh][r][sp]);
      float e[6], sum = 0.f;
      #pragma unroll
      for (int sp = 0; sp < 6; ++sp) { e[sp] = expf(attw[hh][r][sp] - mx); sum += e[sp]; }
      float inv = 1.f / sum;
      #pragma unroll
      for (int sp = 0; sp < 6; ++sp) attw[hh][r][sp] = e[sp] * inv;
    }
    __syncthreads();

    // ---- o = a @ v (thread owns output column tid = hh*32+c) ----
    float oreg[NROW];
    {
      int hh = tid >> 5, c = tid & 31;
      #pragma unroll
      for (int r = 0; r < NROW; ++r) {
        int tt6 = (r / 6) * 6;
        float o = 0.f;
        #pragma unroll
        for (int sp = 0; sp < 6; ++sp)
          o += attw[hh][r][sp] * bf2f(qkvs[tt6 + sp][512 + hh*32 + c]);
        oreg[r] = o;
      }
    }
    __syncthreads();                 // everyone done reading qkvs
    #pragma unroll
    for (int r = 0; r < NROW; ++r) fbuf[r][tid] = oreg[r];
    __syncthreads();

    // ---- attn = o @ Wo + bo ; z = h + attn + res ; LN1 ----
    {
      float bod = bo_l[tid];
      #pragma unroll
      for (int r = 0; r < NROW; ++r) z[r] = bod;
      #pragma unroll 4
      for (int kk = 0; kk < 256; ++kk) {
        float w = Wo_l[kk*256 + tid];
        #pragma unroll
        for (int r = 0; r < NROW; ++r) z[r] += fbuf[r][kk] * w;
      }
      #pragma unroll
      for (int r = 0; r < NROW; ++r) z[r] += hs[r][tid] + resv[r];
    }
    ln24_norm(z, redbuf, n1g[l*256 + tid], n1b[l*256 + tid], tid);
    #pragma unroll
    for (int r = 0; r < NROW; ++r) hs[r][tid] = z[r];
    __syncthreads();

    // ---- FFN: gelu(h@W1+b1)@W2+b2 in 4 hidden chunks of 256 ----
    float ff[NROW];
    {
      float b2d = b2_l[tid];
      #pragma unroll
      for (int r = 0; r < NROW; ++r) ff[r] = b2d;
    }
    for (int ch = 0; ch < 4; ++ch) {
      int j = ch*256 + tid;
      float gv[NROW];
      float b1j = b1_l[j];
      #pragma unroll
      for (int r = 0; r < NROW; ++r) gv[r] = b1j;
      #pragma unroll 4
      for (int kk = 0; kk < 256; ++kk) {
        float w = W1_l[kk*1024 + j];
        #pragma unroll
        for (int r = 0; r < NROW; ++r) gv[r] += hs[r][kk] * w;
      }
      __syncthreads();   // previous fbuf readers done
      #pragma unroll
      for (int r = 0; r < NROW; ++r) {
        float xg = gv[r];
        fbuf[r][tid] = 0.5f * xg * (1.f + erff(xg * 0.70710678118654752f));
      }
      __syncthreads();
      #pragma unroll 4
      for (int kk = 0; kk < 256; ++kk) {
        float w = W2_l[(ch*256 + kk)*256 + tid];
        #pragma unroll
        for (int r = 0; r < NROW; ++r) ff[r] += fbuf[r][kk] * w;
      }
    }
    #pragma unroll
    for (int r = 0; r < NROW; ++r) ff[r] += hs[r][tid] + resv[r];
    ln24_norm(ff, redbuf, n2g[l*256 + tid], n2b[l*256 + tid], tid);
    #pragma unroll
    for (int r = 0; r < NROW; ++r) hs[r][tid] = ff[r];
  }

  // ---------------- output: h[:,0] only ----------------
  __syncthreads();
  #pragma unroll
  for (int tt = 0; tt < TB; ++tt)
    out[(bt*TB + tt)*256 + tid] = hs[tt*6][tid];
}

extern "C" void kernel_launch(void* const* d_in, const int* in_sizes, int n_in,
                              void* d_out, int out_size, void* d_ws, size_t ws_size,
                              hipStream_t stream) {
  (void)in_sizes; (void)n_in; (void)d_ws; (void)ws_size; (void)out_size;
  const float* x      = (const float*)d_in[0];
  const float* W_raw  = (const float*)d_in[1];
  const float* b_raw  = (const float*)d_in[2];
  const float* wl_emb = (const float*)d_in[3];
  const float* pos_emb= (const float*)d_in[4];
  const float* hop_emb= (const float*)d_in[5];
  const float* ln_g   = (const float*)d_in[6];
  const float* ln_b   = (const float*)d_in[7];
  const float* Wqkv   = (const float*)d_in[8];
  const float* bqkv   = (const float*)d_in[9];
  const float* Wo     = (const float*)d_in[10];
  const float* bo     = (const float*)d_in[11];
  const float* n1g    = (const float*)d_in[12];
  const float* n1b    = (const float*)d_in[13];
  const float* W1     = (const float*)d_in[14];
  const float* b1     = (const float*)d_in[15];
  const float* W2     = (const float*)d_in[16];
  const float* b2     = (const float*)d_in[17];
  const float* n2g    = (const float*)d_in[18];
  const float* n2b    = (const float*)d_in[19];
  const float* W_res  = (const float*)d_in[20];
  const float* b_res  = (const float*)d_in[21];
  // d_in[22..24] = edge_index, batch, num_graphs: unused by the reference.

  gb_fused_kernel<<<8192, 256, 0, stream>>>(
      x, W_raw, b_raw, wl_emb, pos_emb, hop_emb, ln_g, ln_b,
      Wqkv, bqkv, Wo, bo, n1g, n1b, W1, b1, W2, b2, n2g, n2b,
      W_res, b_res, (float*)d_out);
}

// Round 3
// 8036.056 us; speedup vs baseline: 3.2762x; 3.2762x over previous
//
#include <hip/hip_runtime.h>
#include <hip/hip_bf16.h>

// GraphBertEncoder: T=32768 tokens, S=6, D=256, H=8 (hd=32), L=4.
// MFMA version: prep kernel packs GEMM weights bf16 fragment-linear into d_ws;
// main kernel does the 4 big GEMMs on v_mfma_f32_16x16x32_bf16 with h/o/g
// staged bf16 in XOR-swizzled LDS. Residual stream stays fp32 in registers.

#define TB 4
#define NROW 24     // TB*S
#define QSTR 776    // qkvs padded stride (bf16 elems)

typedef float f32x4 __attribute__((ext_vector_type(4)));
typedef short bfv8  __attribute__((ext_vector_type(8)));   // 8 bf16 = 4 VGPR

__device__ __forceinline__ float bf2f(__hip_bfloat16 v) { return __bfloat162float(v); }
__device__ __forceinline__ __hip_bfloat16 f2bf(float v) { return __float2bfloat16(v); }
// swizzled byte offset into a [32][256] bf16 tile (row stride 512B)
__device__ __forceinline__ int swz(int row, int cb) { return row*512 + (cb ^ ((row & 7) << 4)); }
__device__ __forceinline__ float gelu_f(float v) { return 0.5f * v * (1.f + erff(v * 0.70710678118654752f)); }

// ws fragment-layout offsets (bf16 elements)
#define OWQ 0u
#define OWO 786432u
#define OW1 1048576u
#define OW2 2097152u
#define WS_ELEMS 3145728u   // *2B = 6291456 bytes

// ---------------------------------------------------------------------------
// prep: fp32 weights -> bf16 B-fragment-linear in ws.
// fragment f of a KxN weight: lane l, j  holds W[ks*32+(l>>4)*8+j][nt*16+(l&15)]
// stored at  base + f*512 + l*8 + j,  f = nt*(K/32) + ks.
__global__ __launch_bounds__(256) void gb_prep_kernel(
    const float* __restrict__ Wqkv, const float* __restrict__ Wo,
    const float* __restrict__ W1,   const float* __restrict__ W2,
    __hip_bfloat16* __restrict__ ws)
{
  int fg   = blockIdx.x * 4 + (threadIdx.x >> 6);   // 0..6143
  int lane = threadIdx.x & 63;
  int layer = fg / 1536, r = fg % 1536;
  const float* src; int K, N, fl; unsigned dstbase;
  if (r < 384)       { src = Wqkv + layer*196608; K = 256;  N = 768;  fl = r;       dstbase = OWQ + layer*196608u; }
  else if (r < 512)  { src = Wo   + layer*65536;  K = 256;  N = 256;  fl = r - 384; dstbase = OWO + layer*65536u;  }
  else if (r < 1024) { src = W1   + layer*262144; K = 256;  N = 1024; fl = r - 512; dstbase = OW1 + layer*262144u; }
  else               { src = W2   + layer*262144; K = 1024; N = 256;  fl = r - 1024;dstbase = OW2 + layer*262144u; }
  int nk = K >> 5;
  int nt = fl / nk, ks = fl % nk;
  int n  = nt*16 + (lane & 15);
  int k0 = ks*32 + (lane >> 4)*8;
  __align__(16) __hip_bfloat16 tmp[8];
  #pragma unroll
  for (int j = 0; j < 8; ++j) tmp[j] = f2bf(src[(size_t)(k0 + j)*N + n]);
  *(uint4*)(ws + dstbase + (unsigned)fl*512u + lane*8) = *(const uint4*)tmp;
}

// ---------------------------------------------------------------------------
__device__ __forceinline__ void ln24_norm(float* z, float* redbuf, float g, float b, int tid) {
  const int lane = tid & 63, wid = tid >> 6;
  #pragma unroll
  for (int cb = 0; cb < 3; ++cb) {
    float s1[8], s2[8];
    #pragma unroll
    for (int q = 0; q < 8; ++q) { float v = z[cb*8+q]; s1[q] = v; s2[q] = v*v; }
    #pragma unroll
    for (int off = 32; off; off >>= 1) {
      #pragma unroll
      for (int q = 0; q < 8; ++q) {
        s1[q] += __shfl_down(s1[q], off, 64);
        s2[q] += __shfl_down(s2[q], off, 64);
      }
    }
    if (lane == 0) {
      #pragma unroll
      for (int q = 0; q < 8; ++q) { redbuf[wid*16+q] = s1[q]; redbuf[wid*16+8+q] = s2[q]; }
    }
    __syncthreads();
    #pragma unroll
    for (int q = 0; q < 8; ++q) {
      float S1 = redbuf[q] + redbuf[16+q] + redbuf[32+q] + redbuf[48+q];
      float S2 = redbuf[8+q] + redbuf[24+q] + redbuf[40+q] + redbuf[56+q];
      float m  = S1 * (1.0f/256.0f);
      float var = S2 * (1.0f/256.0f) - m*m;
      float iv = rsqrtf(var + 1e-5f);
      z[cb*8+q] = (z[cb*8+q] - m) * iv * g + b;
    }
    __syncthreads();
  }
}

__global__ __launch_bounds__(256, 2) void gb_mfma_kernel(
    const float* __restrict__ x,
    const float* __restrict__ W_raw, const float* __restrict__ b_raw,
    const float* __restrict__ wl_emb, const float* __restrict__ pos_emb,
    const float* __restrict__ hop_emb,
    const float* __restrict__ ln_g, const float* __restrict__ ln_b,
    const float* __restrict__ bqkv, const float* __restrict__ bo,
    const float* __restrict__ n1g,  const float* __restrict__ n1b,
    const float* __restrict__ b1,   const float* __restrict__ b2,
    const float* __restrict__ n2g,  const float* __restrict__ n2b,
    const float* __restrict__ W_res, const float* __restrict__ b_res,
    const __hip_bfloat16* __restrict__ wf,
    float* __restrict__ out)
{
  // LDS carve: hsb 16K | unionA 37248 (qkvs|fbuf|xbuf) | unionB 16K (obuf|gbuf)
  //            attw 6144 | redbuf 256  => 76416 B  (2 blocks/CU)
  __shared__ __align__(16) char smem[76416];
  char* hsbC = smem;                           // [32][256] bf16 swizzled
  char* uA   = smem + 16384;
  char* uB   = smem + 16384 + 37248;           // [32][256] bf16 swizzled
  float (*attw)[24][8] = (float (*)[24][8])(smem + 16384 + 37248 + 16384);
  float* redbuf = (float*)(smem + 16384 + 37248 + 16384 + 6144);

  __hip_bfloat16 (*qkvs)[QSTR] = (__hip_bfloat16 (*)[QSTR])uA;
  float (*fbuf)[258] = (float (*)[258])uA;
  float (*xbuf)[128] = (float (*)[128])uA;

  const int tid  = threadIdx.x;
  const int bt   = blockIdx.x;
  const int lane = tid & 63, wid = tid >> 6;
  const int l15  = lane & 15, l4 = lane >> 4;

  // ---------------- Embedding ----------------
  for (int idx = tid; idx < TB*6*128; idx += 256) {
    int tt = idx / 768, rem = idx % 768;
    int s = rem >> 7, f = rem & 127;
    int t = bt*TB + tt, g = t >> 7, i = t & 127;
    int node;
    if (s < 2) node = i;
    else { int j = s - 2; node = (j < i) ? j : (j + 1); }
    xbuf[tt*6+s][f] = x[(g*128 + node)*128 + f];
  }
  __syncthreads();

  float z[NROW];
  {
    #pragma unroll
    for (int r = 0; r < NROW; ++r) z[r] = 0.f;
    #pragma unroll 4
    for (int f = 0; f < 128; ++f) {
      float w = W_raw[f*256 + tid];
      #pragma unroll
      for (int r = 0; r < NROW; ++r) z[r] += xbuf[r][f] * w;
    }
    float br  = b_raw[tid];
    float wl  = wl_emb[tid];
    float hp0 = hop_emb[5*256 + tid];
    float hp1 = hop_emb[511*256 + tid];
    float p[6];
    #pragma unroll
    for (int s = 0; s < 6; ++s) p[s] = pos_emb[s*256 + tid];
    #pragma unroll
    for (int r = 0; r < NROW; ++r) {
      int s = r % 6;
      z[r] += br + p[s] + wl + ((s < 2) ? hp0 : hp1);
    }
  }
  ln24_norm(z, redbuf, ln_g[tid], ln_b[tid], tid);
  #pragma unroll
  for (int r = 0; r < NROW; ++r)
    *(__hip_bfloat16*)(hsbC + swz(r, tid*2)) = f2bf(z[r]);

  // ---------------- res (bt<64 only) ----------------
  float resv[NROW];
  #pragma unroll
  for (int r = 0; r < NROW; ++r) resv[r] = 0.f;
  if (bt < 64) {
    for (int idx = tid; idx < TB*6*128; idx += 256) {
      int tt = idx / 768, rem = idx % 768;
      int s = rem >> 7, f = rem & 127;
      int t = bt*TB + tt;
      xbuf[tt*6+s][f] = x[(t*128 + s)*128 + f];
    }
    __syncthreads();
    #pragma unroll 4
    for (int f = 0; f < 128; ++f) {
      float w = W_res[f*256 + tid];
      #pragma unroll
      for (int r = 0; r < NROW; ++r) resv[r] += xbuf[r][f] * w;
    }
    float brr = b_res[tid];
    #pragma unroll
    for (int r = 0; r < NROW; ++r) resv[r] += brr;
  }

  // ---------------- layers ----------------
  for (int l = 0; l < 4; ++l) {
    const float* bqkv_l = bqkv + l*768;
    const float* bo_l   = bo   + l*256;
    const float* b1_l   = b1   + l*1024;
    const float* b2_l   = b2   + l*256;
    const __hip_bfloat16* WQf = wf + OWQ + (unsigned)l*196608u;
    const __hip_bfloat16* WOf = wf + OWO + (unsigned)l*65536u;
    const __hip_bfloat16* W1f = wf + OW1 + (unsigned)l*262144u;
    const __hip_bfloat16* W2f = wf + OW2 + (unsigned)l*262144u;

    __syncthreads();   // hsb writes visible; uA free for qkvs

    // ---- QKV (M=32 padded, N=768, K=256) ----
    {
      bfv8 a0[8], a1[8];
      #pragma unroll
      for (int ks = 0; ks < 8; ++ks) {
        a0[ks] = *(const bfv8*)(hsbC + swz(l15,      ks*64 + l4*16));
        a1[ks] = *(const bfv8*)(hsbC + swz(16 + l15, ks*64 + l4*16));
      }
      for (int nti = 0; nti < 12; ++nti) {
        int nt = wid + nti*4;
        const __hip_bfloat16* bp = WQf + (unsigned)(nt*8)*512u + lane*8;
        bfv8 bv[8];
        #pragma unroll
        for (int ks = 0; ks < 8; ++ks) bv[ks] = *(const bfv8*)(bp + ks*512);
        f32x4 c0 = {0.f,0.f,0.f,0.f}, c1 = {0.f,0.f,0.f,0.f};
        #pragma unroll
        for (int ks = 0; ks < 8; ++ks) {
          c0 = __builtin_amdgcn_mfma_f32_16x16x32_bf16(a0[ks], bv[ks], c0, 0, 0, 0);
          c1 = __builtin_amdgcn_mfma_f32_16x16x32_bf16(a1[ks], bv[ks], c1, 0, 0, 0);
        }
        int col = nt*16 + l15;
        float bb = bqkv_l[col];
        #pragma unroll
        for (int j = 0; j < 4; ++j) {
          int r0 = l4*4 + j;                       // 0..15
          qkvs[r0][col] = f2bf(c0[j] + bb);
          int r1 = 16 + l4*4 + j;                  // 16..31
          if (r1 < NROW) qkvs[r1][col] = f2bf(c1[j] + bb);
        }
      }
    }
    __syncthreads();

    // ---- scores ----
    #pragma unroll 1
    for (int it = 0; it < 5; ++it) {
      int idx = it*256 + tid;
      if (idx < 1152) {
        int hh = idx / 144, rem = idx % 144;
        int r = rem / 6, sp = rem % 6;
        int tt6 = (r / 6) * 6;
        float sc = 0.f;
        #pragma unroll
        for (int c = 0; c < 32; ++c)
          sc += bf2f(qkvs[r][hh*32 + c]) * bf2f(qkvs[tt6 + sp][256 + hh*32 + c]);
        attw[hh][r][sp] = sc * 0.17677669529663687f;
      }
    }
    __syncthreads();

    // ---- softmax over 6 ----
    if (tid < 192) {
      int hh = tid / 24, r = tid % 24;
      float mx = attw[hh][r][0];
      #pragma unroll
      for (int sp = 1; sp < 6; ++sp) mx = fmaxf(mx, attw[hh][r][sp]);
      float e[6], sum = 0.f;
      #pragma unroll
      for (int sp = 0; sp < 6; ++sp) { e[sp] = expf(attw[hh][r][sp] - mx); sum += e[sp]; }
      float inv = 1.f / sum;
      #pragma unroll
      for (int sp = 0; sp < 6; ++sp) attw[hh][r][sp] = e[sp] * inv;
    }
    __syncthreads();

    // ---- o = a @ v ----
    float oreg[NROW];
    {
      int hh = tid >> 5, c = tid & 31;
      #pragma unroll
      for (int r = 0; r < NROW; ++r) {
        int tt6 = (r / 6) * 6;
        float o = 0.f;
        #pragma unroll
        for (int sp = 0; sp < 6; ++sp)
          o += attw[hh][r][sp] * bf2f(qkvs[tt6 + sp][512 + hh*32 + c]);
        oreg[r] = o;
      }
    }
    __syncthreads();              // qkvs reads done (uB safe to reuse too)
    #pragma unroll
    for (int r = 0; r < NROW; ++r)
      *(__hip_bfloat16*)(uB + swz(r, tid*2)) = f2bf(oreg[r]);
    __syncthreads();

    // ---- attn = o @ Wo  -> fbuf fp32 ----
    {
      bfv8 a0[8], a1[8];
      #pragma unroll
      for (int ks = 0; ks < 8; ++ks) {
        a0[ks] = *(const bfv8*)(uB + swz(l15,      ks*64 + l4*16));
        a1[ks] = *(const bfv8*)(uB + swz(16 + l15, ks*64 + l4*16));
      }
      for (int nti = 0; nti < 4; ++nti) {
        int nt = wid + nti*4;
        const __hip_bfloat16* bp = WOf + (unsigned)(nt*8)*512u + lane*8;
        bfv8 bv[8];
        #pragma unroll
        for (int ks = 0; ks < 8; ++ks) bv[ks] = *(const bfv8*)(bp + ks*512);
        f32x4 c0 = {0.f,0.f,0.f,0.f}, c1 = {0.f,0.f,0.f,0.f};
        #pragma unroll
        for (int ks = 0; ks < 8; ++ks) {
          c0 = __builtin_amdgcn_mfma_f32_16x16x32_bf16(a0[ks], bv[ks], c0, 0, 0, 0);
          c1 = __builtin_amdgcn_mfma_f32_16x16x32_bf16(a1[ks], bv[ks], c1, 0, 0, 0);
        }
        int col = nt*16 + l15;
        #pragma unroll
        for (int j = 0; j < 4; ++j) {
          int r0 = l4*4 + j;
          fbuf[r0][col] = c0[j];
          int r1 = 16 + l4*4 + j;
          if (r1 < NROW) fbuf[r1][col] = c1[j];
        }
      }
    }
    __syncthreads();

    // ---- z = h + attn + res ; LN1 ; h -> hsb ----
    {
      float bod = bo_l[tid];
      #pragma unroll
      for (int r = 0; r < NROW; ++r) z[r] += resv[r] + fbuf[r][tid] + bod;
    }
    ln24_norm(z, redbuf, n1g[l*256 + tid], n1b[l*256 + tid], tid);
    #pragma unroll
    for (int r = 0; r < NROW; ++r)
      *(__hip_bfloat16*)(hsbC + swz(r, tid*2)) = f2bf(z[r]);
    // zero fbuf for FFN accumulation (safe: all fbuf reads done before ln24 barriers)
    #pragma unroll
    for (int r = 0; r < NROW; ++r) fbuf[r][tid] = 0.f;
    __syncthreads();

    // ---- FFN: 4 hidden chunks of 256 ----
    for (int ch = 0; ch < 4; ++ch) {
      // W1 chunk -> gelu values in registers
      float gv[4][8];
      {
        bfv8 a0[8], a1[8];
        #pragma unroll
        for (int ks = 0; ks < 8; ++ks) {
          a0[ks] = *(const bfv8*)(hsbC + swz(l15,      ks*64 + l4*16));
          a1[ks] = *(const bfv8*)(hsbC + swz(16 + l15, ks*64 + l4*16));
        }
        for (int nti = 0; nti < 4; ++nti) {
          int nt = wid + nti*4;                 // 0..15 within chunk
          int ntg = ch*16 + nt;                 // global 0..63
          const __hip_bfloat16* bp = W1f + (unsigned)(ntg*8)*512u + lane*8;
          bfv8 bv[8];
          #pragma unroll
          for (int ks = 0; ks < 8; ++ks) bv[ks] = *(const bfv8*)(bp + ks*512);
          f32x4 c0 = {0.f,0.f,0.f,0.f}, c1 = {0.f,0.f,0.f,0.f};
          #pragma unroll
          for (int ks = 0; ks < 8; ++ks) {
            c0 = __builtin_amdgcn_mfma_f32_16x16x32_bf16(a0[ks], bv[ks], c0, 0, 0, 0);
            c1 = __builtin_amdgcn_mfma_f32_16x16x32_bf16(a1[ks], bv[ks], c1, 0, 0, 0);
          }
          float bb = b1_l[ch*256 + nt*16 + l15];
          #pragma unroll
          for (int j = 0; j < 4; ++j) {
            gv[nti][j]     = gelu_f(c0[j] + bb);
            gv[nti][4 + j] = gelu_f(c1[j] + bb);
          }
        }
      }
      __syncthreads();           // prev chunk's W2 done reading uB
      #pragma unroll
      for (int nti = 0; nti < 4; ++nti) {
        int col = (wid + nti*4)*16 + l15;
        #pragma unroll
        for (int j = 0; j < 4; ++j) {
          int r0 = l4*4 + j;
          *(__hip_bfloat16*)(uB + swz(r0, col*2)) = f2bf(gv[nti][j]);
          int r1 = 16 + l4*4 + j;
          if (r1 < NROW) *(__hip_bfloat16*)(uB + swz(r1, col*2)) = f2bf(gv[nti][4 + j]);
        }
      }
      __syncthreads();

      // W2 partial: fbuf += g @ W2[ch]
      {
        bfv8 g0[8], g1[8];
        #pragma unroll
        for (int ks = 0; ks < 8; ++ks) {
          g0[ks] = *(const bfv8*)(uB + swz(l15,      ks*64 + l4*16));
          g1[ks] = *(const bfv8*)(uB + swz(16 + l15, ks*64 + l4*16));
        }
        for (int nti = 0; nti < 4; ++nti) {
          int nt = wid + nti*4;                 // 0..15
          const __hip_bfloat16* bp = W2f + (unsigned)(nt*32 + ch*8)*512u + lane*8;
          bfv8 bv[8];
          #pragma unroll
          for (int ks = 0; ks < 8; ++ks) bv[ks] = *(const bfv8*)(bp + ks*512);
          f32x4 c0 = {0.f,0.f,0.f,0.f}, c1 = {0.f,0.f,0.f,0.f};
          #pragma unroll
          for (int ks = 0; ks < 8; ++ks) {
            c0 = __builtin_amdgcn_mfma_f32_16x16x32_bf16(g0[ks], bv[ks], c0, 0, 0, 0);
            c1 = __builtin_amdgcn_mfma_f32_16x16x32_bf16(g1[ks], bv[ks], c1, 0, 0, 0);
          }
          int col = nt*16 + l15;
          #pragma unroll
          for (int j = 0; j < 4; ++j) {
            int r0 = l4*4 + j;
            fbuf[r0][col] += c0[j];
            int r1 = 16 + l4*4 + j;
            if (r1 < NROW) fbuf[r1][col] += c1[j];
          }
        }
      }
      __syncthreads();
    }

    // ---- z = h1 + ff + res ; LN2 ; h -> hsb ----
    {
      float b2d = b2_l[tid];
      #pragma unroll
      for (int r = 0; r < NROW; ++r) z[r] += resv[r] + fbuf[r][tid] + b2d;
    }
    ln24_norm(z, redbuf, n2g[l*256 + tid], n2b[l*256 + tid], tid);
    #pragma unroll
    for (int r = 0; r < NROW; ++r)
      *(__hip_bfloat16*)(hsbC + swz(r, tid*2)) = f2bf(z[r]);
  }

  // ---------------- output: h[:,0] ----------------
  #pragma unroll
  for (int tt = 0; tt < TB; ++tt)
    out[(bt*TB + tt)*256 + tid] = z[tt*6];
}

// ---------------------------------------------------------------------------
// Fallback (round-2 pure-VALU kernel) if ws is too small for weight staging.
__global__ __launch_bounds__(256, 2) void gb_fused_fallback(
    const float* __restrict__ x,
    const float* __restrict__ W_raw, const float* __restrict__ b_raw,
    const float* __restrict__ wl_emb, const float* __restrict__ pos_emb,
    const float* __restrict__ hop_emb,
    const float* __restrict__ ln_g, const float* __restrict__ ln_b,
    const float* __restrict__ Wqkv, const float* __restrict__ bqkv,
    const float* __restrict__ Wo,   const float* __restrict__ bo,
    const float* __restrict__ n1g,  const float* __restrict__ n1b,
    const float* __restrict__ W1,   const float* __restrict__ b1,
    const float* __restrict__ W2,   const float* __restrict__ b2,
    const float* __restrict__ n2g,  const float* __restrict__ n2b,
    const float* __restrict__ W_res, const float* __restrict__ b_res,
    float* __restrict__ out)
{
  __shared__ float hs[NROW][256];
  __shared__ __align__(16) char bufraw[NROW*768*2];
  __shared__ float attw[8][NROW][8];
  __shared__ float redbuf[64];

  __hip_bfloat16 (*qkvs)[768] = (__hip_bfloat16 (*)[768])bufraw;
  float (*fbuf)[256] = (float (*)[256])bufraw;
  float (*xbuf)[128] = (float (*)[128])bufraw;

  const int tid = threadIdx.x;
  const int bt  = blockIdx.x;

  for (int idx = tid; idx < TB*6*128; idx += 256) {
    int tt = idx / 768, rem = idx % 768;
    int s = rem >> 7, f = rem & 127;
    int t = bt*TB + tt, g = t >> 7, i = t & 127;
    int node;
    if (s < 2) node = i;
    else { int j = s - 2; node = (j < i) ? j : (j + 1); }
    xbuf[tt*6+s][f] = x[(g*128 + node)*128 + f];
  }
  __syncthreads();

  float z[NROW];
  {
    #pragma unroll
    for (int r = 0; r < NROW; ++r) z[r] = 0.f;
    #pragma unroll 4
    for (int f = 0; f < 128; ++f) {
      float w = W_raw[f*256 + tid];
      #pragma unroll
      for (int r = 0; r < NROW; ++r) z[r] += xbuf[r][f] * w;
    }
    float br  = b_raw[tid];
    float wl  = wl_emb[tid];
    float hp0 = hop_emb[5*256 + tid];
    float hp1 = hop_emb[511*256 + tid];
    float p[6];
    #pragma unroll
    for (int s = 0; s < 6; ++s) p[s] = pos_emb[s*256 + tid];
    #pragma unroll
    for (int r = 0; r < NROW; ++r) {
      int s = r % 6;
      z[r] += br + p[s] + wl + ((s < 2) ? hp0 : hp1);
    }
  }
  ln24_norm(z, redbuf, ln_g[tid], ln_b[tid], tid);
  #pragma unroll
  for (int r = 0; r < NROW; ++r) hs[r][tid] = z[r];

  float resv[NROW];
  #pragma unroll
  for (int r = 0; r < NROW; ++r) resv[r] = 0.f;
  if (bt < 64) {
    for (int idx = tid; idx < TB*6*128; idx += 256) {
      int tt = idx / 768, rem = idx % 768;
      int s = rem >> 7, f = rem & 127;
      int t = bt*TB + tt;
      xbuf[tt*6+s][f] = x[(t*128 + s)*128 + f];
    }
    __syncthreads();
    #pragma unroll 4
    for (int f = 0; f < 128; ++f) {
      float w = W_res[f*256 + tid];
      #pragma unroll
      for (int r = 0; r < NROW; ++r) resv[r] += xbuf[r][f] * w;
    }
    float brr = b_res[tid];
    #pragma unroll
    for (int r = 0; r < NROW; ++r) resv[r] += brr;
  }

  for (int l = 0; l < 4; ++l) {
    const float* Wqkv_l = Wqkv + l*196608;
    const float* bqkv_l = bqkv + l*768;
    const float* Wo_l   = Wo   + l*65536;
    const float* bo_l   = bo   + l*256;
    const float* W1_l   = W1   + l*262144;
    const float* b1_l   = b1   + l*1024;
    const float* W2_l   = W2   + l*262144;
    const float* b2_l   = b2   + l*256;

    __syncthreads();

    for (int cg = 0; cg < 3; ++cg) {
      int col = cg*256 + tid;
      float acc[NROW];
      #pragma unroll
      for (int r = 0; r < NROW; ++r) acc[r] = 0.f;
      #pragma unroll 4
      for (int kk = 0; kk < 256; ++kk) {
        float w = Wqkv_l[kk*768 + col];
        #pragma unroll
        for (int r = 0; r < NROW; ++r) acc[r] += hs[r][kk] * w;
      }
      float bb = bqkv_l[col];
      #pragma unroll
      for (int r = 0; r < NROW; ++r) qkvs[r][col] = f2bf(acc[r] + bb);
    }
    __syncthreads();

    #pragma unroll 1
    for (int it = 0; it < 5; ++it) {
      int idx = it*256 + tid;
      if (idx < 1152) {
        int hh = idx / 144, rem = idx % 144;
        int r = rem / 6, sp = rem % 6;
        int tt6 = (r / 6) * 6;
        float sc = 0.f;
        #pragma unroll
        for (int c = 0; c < 32; ++c)
          sc += bf2f(qkvs[r][hh*32 + c]) * bf2f(qkvs[tt6 + sp][256 + hh*32 + c]);
        attw[hh][r][sp] = sc * 0.17677669529663687f;
      }
    }
    __syncthreads();

    if (tid < 192) {
      int hh = tid / 24, r = tid % 24;
      float mx = attw[hh][r][0];
      #pragma unroll
      for (int sp = 1; sp < 6; ++sp) mx = fmaxf(mx, attw[hh][r][sp]);
      float e[6], sum = 0.f;
      #pragma unroll
      for (int sp = 0; sp < 6; ++sp) { e[sp] = expf(attw[hh][r][sp] - mx); sum += e[sp]; }
      float inv = 1.f / sum;
      #pragma unroll
      for (int sp = 0; sp < 6; ++sp) attw[hh][r][sp] = e[sp] * inv;
    }
    __syncthreads();

    float oreg[NROW];
    {
      int hh = tid >> 5, c = tid & 31;
      #pragma unroll
      for (int r = 0; r < NROW; ++r) {
        int tt6 = (r / 6) * 6;
        float o = 0.f;
        #pragma unroll
        for (int sp = 0; sp < 6; ++sp)
          o += attw[hh][r][sp] * bf2f(qkvs[tt6 + sp][512 + hh*32 + c]);
        oreg[r] = o;
      }
    }
    __syncthreads();
    #pragma unroll
    for (int r = 0; r < NROW; ++r) fbuf[r][tid] = oreg[r];
    __syncthreads();

    {
      float bod = bo_l[tid];
      #pragma unroll
      for (int r = 0; r < NROW; ++r) z[r] = bod;
      #pragma unroll 4
      for (int kk = 0; kk < 256; ++kk) {
        float w = Wo_l[kk*256 + tid];
        #pragma unroll
        for (int r = 0; r < NROW; ++r) z[r] += fbuf[r][kk] * w;
      }
      #pragma unroll
      for (int r = 0; r < NROW; ++r) z[r] += hs[r][tid] + resv[r];
    }
    ln24_norm(z, redbuf, n1g[l*256 + tid], n1b[l*256 + tid], tid);
    #pragma unroll
    for (int r = 0; r < NROW; ++r) hs[r][tid] = z[r];
    __syncthreads();

    float ff[NROW];
    {
      float b2d = b2_l[tid];
      #pragma unroll
      for (int r = 0; r < NROW; ++r) ff[r] = b2d;
    }
    for (int ch = 0; ch < 4; ++ch) {
      int j = ch*256 + tid;
      float gvv[NROW];
      float b1j = b1_l[j];
      #pragma unroll
      for (int r = 0; r < NROW; ++r) gvv[r] = b1j;
      #pragma unroll 4
      for (int kk = 0; kk < 256; ++kk) {
        float w = W1_l[kk*1024 + j];
        #pragma unroll
        for (int r = 0; r < NROW; ++r) gvv[r] += hs[r][kk] * w;
      }
      __syncthreads();
      #pragma unroll
      for (int r = 0; r < NROW; ++r) {
        float xg = gvv[r];
        fbuf[r][tid] = 0.5f * xg * (1.f + erff(xg * 0.70710678118654752f));
      }
      __syncthreads();
      #pragma unroll 4
      for (int kk = 0; kk < 256; ++kk) {
        float w = W2_l[(ch*256 + kk)*256 + tid];
        #pragma unroll
        for (int r = 0; r < NROW; ++r) ff[r] += fbuf[r][kk] * w;
      }
    }
    #pragma unroll
    for (int r = 0; r < NROW; ++r) ff[r] += hs[r][tid] + resv[r];
    ln24_norm(ff, redbuf, n2g[l*256 + tid], n2b[l*256 + tid], tid);
    #pragma unroll
    for (int r = 0; r < NROW; ++r) hs[r][tid] = ff[r];
  }

  __syncthreads();
  #pragma unroll
  for (int tt = 0; tt < TB; ++tt)
    out[(bt*TB + tt)*256 + tid] = hs[tt*6][tid];
}

extern "C" void kernel_launch(void* const* d_in, const int* in_sizes, int n_in,
                              void* d_out, int out_size, void* d_ws, size_t ws_size,
                              hipStream_t stream) {
  (void)in_sizes; (void)n_in; (void)out_size;
  const float* x      = (const float*)d_in[0];
  const float* W_raw  = (const float*)d_in[1];
  const float* b_raw  = (const float*)d_in[2];
  const float* wl_emb = (const float*)d_in[3];
  const float* pos_emb= (const float*)d_in[4];
  const float* hop_emb= (const float*)d_in[5];
  const float* ln_g   = (const float*)d_in[6];
  const float* ln_b   = (const float*)d_in[7];
  const float* Wqkv   = (const float*)d_in[8];
  const float* bqkv   = (const float*)d_in[9];
  const float* Wo     = (const float*)d_in[10];
  const float* bo     = (const float*)d_in[11];
  const float* n1g    = (const float*)d_in[12];
  const float* n1b    = (const float*)d_in[13];
  const float* W1     = (const float*)d_in[14];
  const float* b1     = (const float*)d_in[15];
  const float* W2     = (const float*)d_in[16];
  const float* b2     = (const float*)d_in[17];
  const float* n2g    = (const float*)d_in[18];
  const float* n2b    = (const float*)d_in[19];
  const float* W_res  = (const float*)d_in[20];
  const float* b_res  = (const float*)d_in[21];

  if (ws_size >= (size_t)WS_ELEMS * 2) {
    __hip_bfloat16* wsb = (__hip_bfloat16*)d_ws;
    gb_prep_kernel<<<1536, 256, 0, stream>>>(Wqkv, Wo, W1, W2, wsb);
    gb_mfma_kernel<<<8192, 256, 0, stream>>>(
        x, W_raw, b_raw, wl_emb, pos_emb, hop_emb, ln_g, ln_b,
        bqkv, bo, n1g, n1b, b1, b2, n2g, n2b, W_res, b_res,
        wsb, (float*)d_out);
  } else {
    gb_fused_fallback<<<8192, 256, 0, stream>>>(
        x, W_raw, b_raw, wl_emb, pos_emb, hop_emb, ln_g, ln_b,
        Wqkv, bqkv, Wo, bo, n1g, n1b, W1, b1, W2, b2, n2g, n2b,
        W_res, b_res, (float*)d_out);
  }
}

// Round 4
// 6408.917 us; speedup vs baseline: 4.1080x; 1.2539x over previous
//
#include <hip/hip_runtime.h>
#include <hip/hip_bf16.h>

// GraphBertEncoder: T=32768 tokens, S=6, D=256, H=8 (hd=32), L=4.
// Round 4: keep round-3 fused MFMA structure; fix the stall-bound profile:
//  - double-buffered B-fragment prefetch in all GEMM sections
//  - split MFMA accumulation chains (4 independent chains of depth 4)
//  - merged 1-pass LayerNorm (2 barriers), fused scores+softmax,
//    W2 accumulation in registers, gelu written from W1 epilogue (dbuf LDS)

#define TB 4
#define NROW 24

typedef float f32x4 __attribute__((ext_vector_type(4)));
typedef short bfv8  __attribute__((ext_vector_type(8)));   // 8 bf16 = 4 VGPR

__device__ __forceinline__ float bf2f(__hip_bfloat16 v) { return __bfloat162float(v); }
__device__ __forceinline__ __hip_bfloat16 f2bf(float v) { return __float2bfloat16(v); }
__device__ __forceinline__ float bfs2f(short s) { return __uint_as_float(((unsigned)(unsigned short)s) << 16); }
// swizzled byte offset into a [32][256] bf16 tile (row stride 512B)
__device__ __forceinline__ int swz(int row, int cb) { return row*512 + (cb ^ ((row & 7) << 4)); }
__device__ __forceinline__ float gelu_f(float v) { return 0.5f*v*(1.f + erff(v*0.70710678118654752f)); }
__device__ __forceinline__ float unpk(unsigned p, int hi) {
  return __uint_as_float(hi ? (p & 0xffff0000u) : (p << 16));
}

// ws fragment-layout offsets (bf16 elements)
#define OWQ 0u
#define OWO 786432u
#define OW1 1048576u
#define OW2 2097152u
#define WS_ELEMS 3145728u   // *2B = 6291456 bytes

// ---------------------------------------------------------------------------
// prep: fp32 weights -> bf16 B-fragment-linear in ws (unchanged from round 3).
__global__ __launch_bounds__(256) void gb_prep_kernel(
    const float* __restrict__ Wqkv, const float* __restrict__ Wo,
    const float* __restrict__ W1,   const float* __restrict__ W2,
    __hip_bfloat16* __restrict__ ws)
{
  int fg   = blockIdx.x * 4 + (threadIdx.x >> 6);   // 0..6143
  int lane = threadIdx.x & 63;
  int layer = fg / 1536, r = fg % 1536;
  const float* src; int K, N, fl; unsigned dstbase;
  if (r < 384)       { src = Wqkv + layer*196608; K = 256;  N = 768;  fl = r;       dstbase = OWQ + layer*196608u; }
  else if (r < 512)  { src = Wo   + layer*65536;  K = 256;  N = 256;  fl = r - 384; dstbase = OWO + layer*65536u;  }
  else if (r < 1024) { src = W1   + layer*262144; K = 256;  N = 1024; fl = r - 512; dstbase = OW1 + layer*262144u; }
  else               { src = W2   + layer*262144; K = 1024; N = 256;  fl = r - 1024;dstbase = OW2 + layer*262144u; }
  int nk = K >> 5;
  int nt = fl / nk, ks = fl % nk;
  int n  = nt*16 + (lane & 15);
  int k0 = ks*32 + (lane >> 4)*8;
  __align__(16) __hip_bfloat16 tmp[8];
  #pragma unroll
  for (int j = 0; j < 8; ++j) tmp[j] = f2bf(src[(size_t)(k0 + j)*N + n]);
  *(uint4*)(ws + dstbase + (unsigned)fl*512u + lane*8) = *(const uint4*)tmp;
}

// ---------------------------------------------------------------------------
// one-pass LayerNorm over 256 columns for 24 rows (thread owns column tid).
__device__ __forceinline__ void ln24_norm(float* z, float* redbuf, float g, float b, int tid) {
  const int lane = tid & 63, wid = tid >> 6;
  float s1[NROW], s2[NROW];
  #pragma unroll
  for (int r = 0; r < NROW; ++r) { float v = z[r]; s1[r] = v; s2[r] = v*v; }
  #pragma unroll
  for (int off = 32; off; off >>= 1) {
    #pragma unroll
    for (int r = 0; r < NROW; ++r) {
      s1[r] += __shfl_down(s1[r], off, 64);
      s2[r] += __shfl_down(s2[r], off, 64);
    }
  }
  if (lane == 0) {
    #pragma unroll
    for (int r = 0; r < NROW; ++r) { redbuf[wid*48 + r] = s1[r]; redbuf[wid*48 + 24 + r] = s2[r]; }
  }
  __syncthreads();
  #pragma unroll
  for (int r = 0; r < NROW; ++r) {
    float S1 = redbuf[r] + redbuf[48+r] + redbuf[96+r] + redbuf[144+r];
    float S2 = redbuf[24+r] + redbuf[72+r] + redbuf[120+r] + redbuf[168+r];
    float m  = S1 * (1.0f/256.0f);
    float var = S2 * (1.0f/256.0f) - m*m;
    float iv = rsqrtf(var + 1e-5f);
    z[r] = (z[r] - m) * iv * g + b;
  }
  __syncthreads();
}

// ---------------------------------------------------------------------------
// GEMM section: per wave, NTI n-tiles (nt = wid + 4*i), K=256 (8 ks-fragments).
// B prefetched double-buffered; 4 independent MFMA chains; epi(i, c0, c1).
// p = weight_base + (first_frag)*512 + lane*8 ; i-step = 4*NKTOT*512 elems.
template<int NTI, int NKTOT, class Epi>
__device__ __forceinline__ void gemm_sec(const __hip_bfloat16* __restrict__ p,
                                         const bfv8 (&a0)[8], const bfv8 (&a1)[8],
                                         Epi epi)
{
  bfv8 bA[8], bB[8];
  #pragma unroll
  for (int k = 0; k < 8; ++k) bA[k] = *(const bfv8*)(p + k*512);
  #pragma unroll
  for (int i = 0; i < NTI; i += 2) {
    {
      const __hip_bfloat16* pn = p + (unsigned)(i+1)*4u*(unsigned)NKTOT*512u;
      #pragma unroll
      for (int k = 0; k < 8; ++k) bB[k] = *(const bfv8*)(pn + k*512);
    }
    {
      f32x4 c0a = {0,0,0,0}, c0b = {0,0,0,0}, c1a = {0,0,0,0}, c1b = {0,0,0,0};
      #pragma unroll
      for (int k = 0; k < 8; k += 2) {
        c0a = __builtin_amdgcn_mfma_f32_16x16x32_bf16(a0[k],   bA[k],   c0a, 0,0,0);
        c1a = __builtin_amdgcn_mfma_f32_16x16x32_bf16(a1[k],   bA[k],   c1a, 0,0,0);
        c0b = __builtin_amdgcn_mfma_f32_16x16x32_bf16(a0[k+1], bA[k+1], c0b, 0,0,0);
        c1b = __builtin_amdgcn_mfma_f32_16x16x32_bf16(a1[k+1], bA[k+1], c1b, 0,0,0);
      }
      epi(i, c0a + c0b, c1a + c1b);
    }
    if (i + 2 < NTI) {
      const __hip_bfloat16* pn = p + (unsigned)(i+2)*4u*(unsigned)NKTOT*512u;
      #pragma unroll
      for (int k = 0; k < 8; ++k) bA[k] = *(const bfv8*)(pn + k*512);
    }
    {
      f32x4 c0a = {0,0,0,0}, c0b = {0,0,0,0}, c1a = {0,0,0,0}, c1b = {0,0,0,0};
      #pragma unroll
      for (int k = 0; k < 8; k += 2) {
        c0a = __builtin_amdgcn_mfma_f32_16x16x32_bf16(a0[k],   bB[k],   c0a, 0,0,0);
        c1a = __builtin_amdgcn_mfma_f32_16x16x32_bf16(a1[k],   bB[k],   c1a, 0,0,0);
        c0b = __builtin_amdgcn_mfma_f32_16x16x32_bf16(a0[k+1], bB[k+1], c0b, 0,0,0);
        c1b = __builtin_amdgcn_mfma_f32_16x16x32_bf16(a1[k+1], bB[k+1], c1b, 0,0,0);
      }
      epi(i+1, c0a + c0b, c1a + c1b);
    }
  }
}

// ---------------------------------------------------------------------------
__global__ __launch_bounds__(256, 2) void gb_mfma_kernel(
    const float* __restrict__ x,
    const float* __restrict__ W_raw, const float* __restrict__ b_raw,
    const float* __restrict__ wl_emb, const float* __restrict__ pos_emb,
    const float* __restrict__ hop_emb,
    const float* __restrict__ ln_g, const float* __restrict__ ln_b,
    const float* __restrict__ bqkv, const float* __restrict__ bo,
    const float* __restrict__ n1g,  const float* __restrict__ n1b,
    const float* __restrict__ b1,   const float* __restrict__ b2,
    const float* __restrict__ n2g,  const float* __restrict__ n2b,
    const float* __restrict__ W_res, const float* __restrict__ b_res,
    const __hip_bfloat16* __restrict__ wf,
    float* __restrict__ out)
{
  // LDS: hsb 16K | uA 37248 (xbuf fp32 | qkvs bf16 | fbuf fp32 | gelu dbuf 2x16K)
  //      uB 16K (o swz bf16) | attw 4608 | redbuf 768  => 75392 B (2 blocks/CU)
  __shared__ __align__(16) char smem[75392];
  char* hsb = smem;                              // [32][512B] swz bf16
  char* uA  = smem + 16384;
  char* uB  = smem + 53632;                      // [32][512B] swz bf16
  float (*attw)[24][6] = (float (*)[24][6])(smem + 70016);
  float* redbuf = (float*)(smem + 74624);

  __hip_bfloat16 (*qkvs)[776] = (__hip_bfloat16 (*)[776])uA;
  float (*fbuf)[264] = (float (*)[264])uA;
  float (*xbuf)[128] = (float (*)[128])uA;

  const int tid  = threadIdx.x;
  const int bt   = blockIdx.x;
  const int lane = tid & 63, wid = tid >> 6;
  const int l15  = lane & 15, l4 = lane >> 4;

  // zero rows 24-31 of hsb and uB once (A-fragments read rows 16..31)
  {
    uint4 zz = {0u,0u,0u,0u};
    *(uint4*)(hsb + 24*512 + tid*16) = zz;
    *(uint4*)(uB  + 24*512 + tid*16) = zz;
  }

  // ---------------- Embedding: stage sub_x rows (fp32, idx mapping) --------
  for (int idx = tid; idx < TB*6*128; idx += 256) {
    int tt = idx / 768, rem = idx % 768;
    int s = rem >> 7, f = rem & 127;
    int t = bt*TB + tt, g = t >> 7, i = t & 127;
    int node;
    if (s < 2) node = i;
    else { int j = s - 2; node = (j < i) ? j : (j + 1); }
    xbuf[tt*6+s][f] = x[(g*128 + node)*128 + f];
  }
  __syncthreads();

  float z[NROW];
  {
    #pragma unroll
    for (int r = 0; r < NROW; ++r) z[r] = 0.f;
    #pragma unroll 2
    for (int f4 = 0; f4 < 32; ++f4) {
      float w0 = W_raw[(f4*4+0)*256 + tid];
      float w1 = W_raw[(f4*4+1)*256 + tid];
      float w2 = W_raw[(f4*4+2)*256 + tid];
      float w3 = W_raw[(f4*4+3)*256 + tid];
      #pragma unroll
      for (int r = 0; r < NROW; ++r) {
        float4 xv = *(const float4*)(&xbuf[r][f4*4]);
        z[r] += xv.x*w0 + xv.y*w1 + xv.z*w2 + xv.w*w3;
      }
    }
    float br  = b_raw[tid];
    float wl  = wl_emb[tid];
    float hp0 = hop_emb[5*256 + tid];
    float hp1 = hop_emb[511*256 + tid];
    float p[6];
    #pragma unroll
    for (int s = 0; s < 6; ++s) p[s] = pos_emb[s*256 + tid];
    #pragma unroll
    for (int r = 0; r < NROW; ++r) {
      int s = r % 6;
      z[r] += br + p[s] + wl + ((s < 2) ? hp0 : hp1);
    }
  }
  ln24_norm(z, redbuf, ln_g[tid], ln_b[tid], tid);
  #pragma unroll
  for (int r = 0; r < NROW; ++r)
    *(__hip_bfloat16*)(hsb + swz(r, tid*2)) = f2bf(z[r]);

  // ---------------- res (bt<64 only), packed bf16 pairs --------------------
  unsigned resp[12];
  #pragma unroll
  for (int k = 0; k < 12; ++k) resp[k] = 0u;
  if (bt < 64) {
    __syncthreads();   // embed xbuf reads done everywhere
    for (int idx = tid; idx < TB*6*128; idx += 256) {
      int tt = idx / 768, rem = idx % 768;
      int s = rem >> 7, f = rem & 127;
      int t = bt*TB + tt;
      xbuf[tt*6+s][f] = x[(t*128 + s)*128 + f];
    }
    __syncthreads();
    float resv[NROW];
    float brr = b_res[tid];
    #pragma unroll
    for (int r = 0; r < NROW; ++r) resv[r] = brr;
    #pragma unroll 2
    for (int f4 = 0; f4 < 32; ++f4) {
      float w0 = W_res[(f4*4+0)*256 + tid];
      float w1 = W_res[(f4*4+1)*256 + tid];
      float w2 = W_res[(f4*4+2)*256 + tid];
      float w3 = W_res[(f4*4+3)*256 + tid];
      #pragma unroll
      for (int r = 0; r < NROW; ++r) {
        float4 xv = *(const float4*)(&xbuf[r][f4*4]);
        resv[r] += xv.x*w0 + xv.y*w1 + xv.z*w2 + xv.w*w3;
      }
    }
    #pragma unroll
    for (int k = 0; k < 12; ++k) {
      unsigned lo = __float_as_uint(resv[2*k])   >> 16;   // truncate-to-bf16 ok here
      unsigned hi = __float_as_uint(resv[2*k+1]) & 0xffff0000u;
      resp[k] = hi | lo;
    }
  }

  // ---------------- layers ----------------
  for (int l = 0; l < 4; ++l) {
    const float* bqkv_l = bqkv + l*768;
    const __hip_bfloat16* WQf = wf + OWQ + (unsigned)l*196608u;
    const __hip_bfloat16* WOf = wf + OWO + (unsigned)l*65536u;
    const __hip_bfloat16* W1f = wf + OW1 + (unsigned)l*262144u;
    const __hip_bfloat16* W2f = wf + OW2 + (unsigned)l*262144u;

    float n1gv = n1g[l*256 + tid], n1bv = n1b[l*256 + tid];
    float n2gv = n2g[l*256 + tid], n2bv = n2b[l*256 + tid];
    float bov  = bo[l*256 + tid],  b2v  = b2[l*256 + tid];

    // qkv bias preload (12 n-tiles per wave)
    float bb[12];
    #pragma unroll
    for (int i = 0; i < 12; ++i) bb[i] = bqkv_l[(wid + i*4)*16 + l15];

    __syncthreads();   // hsb ready; uA free for qkvs

    // ---- QKV (N=768, K=256) ----
    {
      bfv8 a0[8], a1[8];
      #pragma unroll
      for (int ks = 0; ks < 8; ++ks) {
        a0[ks] = *(const bfv8*)(hsb + swz(l15,      ks*64 + l4*16));
        a1[ks] = *(const bfv8*)(hsb + swz(16 + l15, ks*64 + l4*16));
      }
      gemm_sec<12, 8>(WQf + (unsigned)wid*8u*512u + lane*8, a0, a1,
        [&](int i, f32x4 c0, f32x4 c1) {
          int col = (wid + i*4)*16 + l15;
          #pragma unroll
          for (int j = 0; j < 4; ++j) {
            qkvs[l4*4 + j][col] = f2bf(c0[j] + bb[i]);
            int r1 = 16 + l4*4 + j;
            if (r1 < NROW) qkvs[r1][col] = f2bf(c1[j] + bb[i]);
          }
        });
    }
    __syncthreads();

    // ---- scores + softmax fused (threads 0..191: (head, row)) ----
    if (tid < 192) {
      int hh = tid / 24, r = tid % 24;
      int tt6 = (r / 6) * 6;
      bfv8 qv[4];
      #pragma unroll
      for (int p4 = 0; p4 < 4; ++p4) qv[p4] = *(const bfv8*)(&qkvs[r][hh*32 + p4*8]);
      float sc[6];
      #pragma unroll
      for (int sp = 0; sp < 6; ++sp) {
        float s = 0.f;
        #pragma unroll
        for (int p4 = 0; p4 < 4; ++p4) {
          bfv8 kv = *(const bfv8*)(&qkvs[tt6 + sp][256 + hh*32 + p4*8]);
          #pragma unroll
          for (int j = 0; j < 8; ++j) s += bfs2f(qv[p4][j]) * bfs2f(kv[j]);
        }
        sc[sp] = s * 0.17677669529663687f;   // 1/sqrt(32)
      }
      float mx = sc[0];
      #pragma unroll
      for (int sp = 1; sp < 6; ++sp) mx = fmaxf(mx, sc[sp]);
      float sum = 0.f;
      #pragma unroll
      for (int sp = 0; sp < 6; ++sp) { sc[sp] = expf(sc[sp] - mx); sum += sc[sp]; }
      float inv = 1.f / sum;
      #pragma unroll
      for (int sp = 0; sp < 6; ++sp) attw[hh][r][sp] = sc[sp] * inv;
    }
    __syncthreads();

    // ---- o = a @ v -> uB (swz bf16). thread owns (head hh, col c) ----
    {
      int hh = tid >> 5, c = tid & 31;
      int col2 = (hh*32 + c)*2;
      #pragma unroll
      for (int tt = 0; tt < 4; ++tt) {
        float vv[6];
        #pragma unroll
        for (int sp = 0; sp < 6; ++sp) vv[sp] = bf2f(qkvs[tt*6 + sp][512 + hh*32 + c]);
        #pragma unroll
        for (int q = 0; q < 6; ++q) {
          float o = 0.f;
          #pragma unroll
          for (int sp = 0; sp < 6; ++sp) o += attw[hh][tt*6 + q][sp] * vv[sp];
          *(__hip_bfloat16*)(uB + swz(tt*6 + q, col2)) = f2bf(o);
        }
      }
    }
    __syncthreads();   // uB ready; qkvs dead -> fbuf writable

    // ---- attn = o @ Wo -> fbuf fp32 ----
    {
      bfv8 a0[8], a1[8];
      #pragma unroll
      for (int ks = 0; ks < 8; ++ks) {
        a0[ks] = *(const bfv8*)(uB + swz(l15,      ks*64 + l4*16));
        a1[ks] = *(const bfv8*)(uB + swz(16 + l15, ks*64 + l4*16));
      }
      gemm_sec<4, 8>(WOf + (unsigned)wid*8u*512u + lane*8, a0, a1,
        [&](int i, f32x4 c0, f32x4 c1) {
          int col = (wid + i*4)*16 + l15;
          #pragma unroll
          for (int j = 0; j < 4; ++j) {
            fbuf[l4*4 + j][col] = c0[j];
            int r1 = 16 + l4*4 + j;
            if (r1 < NROW) fbuf[r1][col] = c1[j];
          }
        });
    }
    __syncthreads();

    // ---- z = h + attn + res ; LN1 ; -> hsb ----
    #pragma unroll
    for (int r = 0; r < NROW; ++r)
      z[r] += unpk(resp[r >> 1], r & 1) + fbuf[r][tid] + bov;
    ln24_norm(z, redbuf, n1gv, n1bv, tid);
    #pragma unroll
    for (int r = 0; r < NROW; ++r)
      *(__hip_bfloat16*)(hsb + swz(r, tid*2)) = f2bf(z[r]);
    // zero rows 24-31 of both gelu buffers (clobbered by qkvs earlier)
    {
      uint4 zz = {0u,0u,0u,0u};
      *(uint4*)(uA + 24*512 + tid*16) = zz;            // gb0 tail
      *(uint4*)(uA + 16384 + 24*512 + tid*16) = zz;    // gb1 tail
    }
    __syncthreads();   // hsb + gelu-tails ready

    // ---- FFN: 4 hidden chunks; gelu -> dbuf LDS; W2 accumulates in regs ----
    {
      bfv8 ah0[8], ah1[8];
      #pragma unroll
      for (int ks = 0; ks < 8; ++ks) {
        ah0[ks] = *(const bfv8*)(hsb + swz(l15,      ks*64 + l4*16));
        ah1[ks] = *(const bfv8*)(hsb + swz(16 + l15, ks*64 + l4*16));
      }
      f32x4 facc[8];
      #pragma unroll
      for (int k = 0; k < 8; ++k) facc[k] = (f32x4){0.f,0.f,0.f,0.f};

      #pragma unroll 1
      for (int ch = 0; ch < 4; ++ch) {
        char* gb = uA + (ch & 1)*16384;
        float bb1[4];
        #pragma unroll
        for (int i = 0; i < 4; ++i) bb1[i] = b1[l*1024 + ch*256 + (wid + i*4)*16 + l15];

        gemm_sec<4, 8>(W1f + (unsigned)(ch*128 + wid*8)*512u + lane*8, ah0, ah1,
          [&](int i, f32x4 c0, f32x4 c1) {
            int col2 = ((wid + i*4)*16 + l15)*2;
            #pragma unroll
            for (int j = 0; j < 4; ++j) {
              *(__hip_bfloat16*)(gb + swz(l4*4 + j, col2)) = f2bf(gelu_f(c0[j] + bb1[i]));
              int r1 = 16 + l4*4 + j;
              if (r1 < NROW)
                *(__hip_bfloat16*)(gb + swz(r1, col2)) = f2bf(gelu_f(c1[j] + bb1[i]));
            }
          });
        __syncthreads();   // gelu chunk ready

        bfv8 g0[8], g1[8];
        #pragma unroll
        for (int ks = 0; ks < 8; ++ks) {
          g0[ks] = *(const bfv8*)(gb + swz(l15,      ks*64 + l4*16));
          g1[ks] = *(const bfv8*)(gb + swz(16 + l15, ks*64 + l4*16));
        }
        gemm_sec<4, 32>(W2f + (unsigned)(wid*32 + ch*8)*512u + lane*8, g0, g1,
          [&](int i, f32x4 c0, f32x4 c1) {
            facc[2*i]   += c0;
            facc[2*i+1] += c1;
          });
      }
      __syncthreads();   // last gelu-buf reads done -> fbuf writable
      #pragma unroll
      for (int i = 0; i < 4; ++i) {
        int col = (wid + i*4)*16 + l15;
        #pragma unroll
        for (int j = 0; j < 4; ++j) {
          fbuf[l4*4 + j][col] = facc[2*i][j];
          int r1 = 16 + l4*4 + j;
          if (r1 < NROW) fbuf[r1][col] = facc[2*i+1][j];
        }
      }
    }
    __syncthreads();

    // ---- z = h1 + ff + res ; LN2 ; -> hsb ----
    #pragma unroll
    for (int r = 0; r < NROW; ++r)
      z[r] += unpk(resp[r >> 1], r & 1) + fbuf[r][tid] + b2v;
    ln24_norm(z, redbuf, n2gv, n2bv, tid);
    #pragma unroll
    for (int r = 0; r < NROW; ++r)
      *(__hip_bfloat16*)(hsb + swz(r, tid*2)) = f2bf(z[r]);
  }

  // ---------------- output: h[:,0] ----------------
  #pragma unroll
  for (int tt = 0; tt < TB; ++tt)
    out[(bt*TB + tt)*256 + tid] = z[tt*6];
}

// ---------------------------------------------------------------------------
// Fallback (round-2 pure-VALU kernel) if ws is too small for weight staging.
__global__ __launch_bounds__(256, 2) void gb_fused_fallback(
    const float* __restrict__ x,
    const float* __restrict__ W_raw, const float* __restrict__ b_raw,
    const float* __restrict__ wl_emb, const float* __restrict__ pos_emb,
    const float* __restrict__ hop_emb,
    const float* __restrict__ ln_g, const float* __restrict__ ln_b,
    const float* __restrict__ Wqkv, const float* __restrict__ bqkv,
    const float* __restrict__ Wo,   const float* __restrict__ bo,
    const float* __restrict__ n1g,  const float* __restrict__ n1b,
    const float* __restrict__ W1,   const float* __restrict__ b1,
    const float* __restrict__ W2,   const float* __restrict__ b2,
    const float* __restrict__ n2g,  const float* __restrict__ n2b,
    const float* __restrict__ W_res, const float* __restrict__ b_res,
    float* __restrict__ out)
{
  __shared__ float hs[NROW][256];
  __shared__ __align__(16) char bufraw[NROW*768*2];
  __shared__ float attw[8][NROW][8];
  __shared__ float redbuf[192];

  __hip_bfloat16 (*qkvs)[768] = (__hip_bfloat16 (*)[768])bufraw;
  float (*fbuf)[256] = (float (*)[256])bufraw;
  float (*xbuf)[128] = (float (*)[128])bufraw;

  const int tid = threadIdx.x;
  const int bt  = blockIdx.x;

  for (int idx = tid; idx < TB*6*128; idx += 256) {
    int tt = idx / 768, rem = idx % 768;
    int s = rem >> 7, f = rem & 127;
    int t = bt*TB + tt, g = t >> 7, i = t & 127;
    int node;
    if (s < 2) node = i;
    else { int j = s - 2; node = (j < i) ? j : (j + 1); }
    xbuf[tt*6+s][f] = x[(g*128 + node)*128 + f];
  }
  __syncthreads();

  float z[NROW];
  {
    #pragma unroll
    for (int r = 0; r < NROW; ++r) z[r] = 0.f;
    #pragma unroll 4
    for (int f = 0; f < 128; ++f) {
      float w = W_raw[f*256 + tid];
      #pragma unroll
      for (int r = 0; r < NROW; ++r) z[r] += xbuf[r][f] * w;
    }
    float br  = b_raw[tid];
    float wl  = wl_emb[tid];
    float hp0 = hop_emb[5*256 + tid];
    float hp1 = hop_emb[511*256 + tid];
    float p[6];
    #pragma unroll
    for (int s = 0; s < 6; ++s) p[s] = pos_emb[s*256 + tid];
    #pragma unroll
    for (int r = 0; r < NROW; ++r) {
      int s = r % 6;
      z[r] += br + p[s] + wl + ((s < 2) ? hp0 : hp1);
    }
  }
  ln24_norm(z, redbuf, ln_g[tid], ln_b[tid], tid);
  #pragma unroll
  for (int r = 0; r < NROW; ++r) hs[r][tid] = z[r];

  float resv[NROW];
  #pragma unroll
  for (int r = 0; r < NROW; ++r) resv[r] = 0.f;
  if (bt < 64) {
    __syncthreads();
    for (int idx = tid; idx < TB*6*128; idx += 256) {
      int tt = idx / 768, rem = idx % 768;
      int s = rem >> 7, f = rem & 127;
      int t = bt*TB + tt;
      xbuf[tt*6+s][f] = x[(t*128 + s)*128 + f];
    }
    __syncthreads();
    #pragma unroll 4
    for (int f = 0; f < 128; ++f) {
      float w = W_res[f*256 + tid];
      #pragma unroll
      for (int r = 0; r < NROW; ++r) resv[r] += xbuf[r][f] * w;
    }
    float brr = b_res[tid];
    #pragma unroll
    for (int r = 0; r < NROW; ++r) resv[r] += brr;
  }

  for (int l = 0; l < 4; ++l) {
    const float* Wqkv_l = Wqkv + l*196608;
    const float* bqkv_l = bqkv + l*768;
    const float* Wo_l   = Wo   + l*65536;
    const float* bo_l   = bo   + l*256;
    const float* W1_l   = W1   + l*262144;
    const float* b1_l   = b1   + l*1024;
    const float* W2_l   = W2   + l*262144;
    const float* b2_l   = b2   + l*256;

    __syncthreads();

    for (int cg = 0; cg < 3; ++cg) {
      int col = cg*256 + tid;
      float acc[NROW];
      #pragma unroll
      for (int r = 0; r < NROW; ++r) acc[r] = 0.f;
      #pragma unroll 4
      for (int kk = 0; kk < 256; ++kk) {
        float w = Wqkv_l[kk*768 + col];
        #pragma unroll
        for (int r = 0; r < NROW; ++r) acc[r] += hs[r][kk] * w;
      }
      float bbv = bqkv_l[col];
      #pragma unroll
      for (int r = 0; r < NROW; ++r) qkvs[r][col] = f2bf(acc[r] + bbv);
    }
    __syncthreads();

    #pragma unroll 1
    for (int it = 0; it < 5; ++it) {
      int idx = it*256 + tid;
      if (idx < 1152) {
        int hh = idx / 144, rem = idx % 144;
        int r = rem / 6, sp = rem % 6;
        int tt6 = (r / 6) * 6;
        float sc = 0.f;
        #pragma unroll
        for (int c = 0; c < 32; ++c)
          sc += bf2f(qkvs[r][hh*32 + c]) * bf2f(qkvs[tt6 + sp][256 + hh*32 + c]);
        attw[hh][r][sp] = sc * 0.17677669529663687f;
      }
    }
    __syncthreads();

    if (tid < 192) {
      int hh = tid / 24, r = tid % 24;
      float mx = attw[hh][r][0];
      #pragma unroll
      for (int sp = 1; sp < 6; ++sp) mx = fmaxf(mx, attw[hh][r][sp]);
      float e[6], sum = 0.f;
      #pragma unroll
      for (int sp = 0; sp < 6; ++sp) { e[sp] = expf(attw[hh][r][sp] - mx); sum += e[sp]; }
      float inv = 1.f / sum;
      #pragma unroll
      for (int sp = 0; sp < 6; ++sp) attw[hh][r][sp] = e[sp] * inv;
    }
    __syncthreads();

    float oreg[NROW];
    {
      int hh = tid >> 5, c = tid & 31;
      #pragma unroll
      for (int r = 0; r < NROW; ++r) {
        int tt6 = (r / 6) * 6;
        float o = 0.f;
        #pragma unroll
        for (int sp = 0; sp < 6; ++sp)
          o += attw[hh][r][sp] * bf2f(qkvs[tt6 + sp][512 + hh*32 + c]);
        oreg[r] = o;
      }
    }
    __syncthreads();
    #pragma unroll
    for (int r = 0; r < NROW; ++r) fbuf[r][tid] = oreg[r];
    __syncthreads();

    {
      float bod = bo_l[tid];
      float zz[NROW];
      #pragma unroll
      for (int r = 0; r < NROW; ++r) zz[r] = bod;
      #pragma unroll 4
      for (int kk = 0; kk < 256; ++kk) {
        float w = Wo_l[kk*256 + tid];
        #pragma unroll
        for (int r = 0; r < NROW; ++r) zz[r] += fbuf[r][kk] * w;
      }
      #pragma unroll
      for (int r = 0; r < NROW; ++r) z[r] += zz[r] + resv[r];
    }
    ln24_norm(z, redbuf, n1g[l*256 + tid], n1b[l*256 + tid], tid);
    #pragma unroll
    for (int r = 0; r < NROW; ++r) hs[r][tid] = z[r];
    __syncthreads();

    float ff[NROW];
    {
      float b2d = b2_l[tid];
      #pragma unroll
      for (int r = 0; r < NROW; ++r) ff[r] = b2d;
    }
    for (int ch = 0; ch < 4; ++ch) {
      int j = ch*256 + tid;
      float gvv[NROW];
      float b1j = b1_l[j];
      #pragma unroll
      for (int r = 0; r < NROW; ++r) gvv[r] = b1j;
      #pragma unroll 4
      for (int kk = 0; kk < 256; ++kk) {
        float w = W1_l[kk*1024 + j];
        #pragma unroll
        for (int r = 0; r < NROW; ++r) gvv[r] += hs[r][kk] * w;
      }
      __syncthreads();
      #pragma unroll
      for (int r = 0; r < NROW; ++r) fbuf[r][tid] = gelu_f(gvv[r]);
      __syncthreads();
      #pragma unroll 4
      for (int kk = 0; kk < 256; ++kk) {
        float w = W2_l[(ch*256 + kk)*256 + tid];
        #pragma unroll
        for (int r = 0; r < NROW; ++r) ff[r] += fbuf[r][kk] * w;
      }
    }
    #pragma unroll
    for (int r = 0; r < NROW; ++r) z[r] += ff[r] - b2_l[tid] + b2_l[tid] + resv[r];
    #pragma unroll
    for (int r = 0; r < NROW; ++r) z[r] = z[r];   // keep structure simple
    ln24_norm(z, redbuf, n2g[l*256 + tid], n2b[l*256 + tid], tid);
    #pragma unroll
    for (int r = 0; r < NROW; ++r) hs[r][tid] = z[r];
  }

  __syncthreads();
  #pragma unroll
  for (int tt = 0; tt < TB; ++tt)
    out[(bt*TB + tt)*256 + tid] = hs[tt*6][tid];
}

extern "C" void kernel_launch(void* const* d_in, const int* in_sizes, int n_in,
                              void* d_out, int out_size, void* d_ws, size_t ws_size,
                              hipStream_t stream) {
  (void)in_sizes; (void)n_in; (void)out_size;
  const float* x      = (const float*)d_in[0];
  const float* W_raw  = (const float*)d_in[1];
  const float* b_raw  = (const float*)d_in[2];
  const float* wl_emb = (const float*)d_in[3];
  const float* pos_emb= (const float*)d_in[4];
  const float* hop_emb= (const float*)d_in[5];
  const float* ln_g   = (const float*)d_in[6];
  const float* ln_b   = (const float*)d_in[7];
  const float* Wqkv   = (const float*)d_in[8];
  const float* bqkv   = (const float*)d_in[9];
  const float* Wo     = (const float*)d_in[10];
  const float* bo     = (const float*)d_in[11];
  const float* n1g    = (const float*)d_in[12];
  const float* n1b    = (const float*)d_in[13];
  const float* W1     = (const float*)d_in[14];
  const float* b1     = (const float*)d_in[15];
  const float* W2     = (const float*)d_in[16];
  const float* b2     = (const float*)d_in[17];
  const float* n2g    = (const float*)d_in[18];
  const float* n2b    = (const float*)d_in[19];
  const float* W_res  = (const float*)d_in[20];
  const float* b_res  = (const float*)d_in[21];

  if (ws_size >= (size_t)WS_ELEMS * 2) {
    __hip_bfloat16* wsb = (__hip_bfloat16*)d_ws;
    gb_prep_kernel<<<1536, 256, 0, stream>>>(Wqkv, Wo, W1, W2, wsb);
    gb_mfma_kernel<<<8192, 256, 0, stream>>>(
        x, W_raw, b_raw, wl_emb, pos_emb, hop_emb, ln_g, ln_b,
        bqkv, bo, n1g, n1b, b1, b2, n2g, n2b, W_res, b_res,
        wsb, (float*)d_out);
  } else {
    gb_fused_fallback<<<8192, 256, 0, stream>>>(
        x, W_raw, b_raw, wl_emb, pos_emb, hop_emb, ln_g, ln_b,
        Wqkv, bqkv, Wo, bo, n1g, n1b, W1, b1, W2, b2, n2g, n2b,
        W_res, b_res, (float*)d_out);
  }
}